// Round 1
// baseline (282202.710 us; speedup 1.0000x reference)
//
#include <hip/hip_runtime.h>
#include <stdint.h>

#define B_ 8
#define S_ 4096
#define DIN 2048
#define DH 512
#define NG3 1536   // 3 gates * DH
#define NG 16      // workgroups per batch element in the scan
#define ROWS 32    // hidden rows owned per scan workgroup (DH/NG)
#define NWG (NG * B_)

typedef __attribute__((ext_vector_type(8))) short bf16x8;
typedef __attribute__((ext_vector_type(4))) float f32x4;

__device__ __forceinline__ unsigned short f2bf(float f) {
  unsigned int u = __builtin_bit_cast(unsigned int, f);
  u = u + 0x7FFFu + ((u >> 16) & 1u);   // RNE
  return (unsigned short)(u >> 16);
}
__device__ __forceinline__ float bf2f(unsigned short h) {
  unsigned int u = ((unsigned int)h) << 16;
  return __builtin_bit_cast(float, u);
}
__device__ __forceinline__ float bflo(unsigned u) {
  return __builtin_bit_cast(float, u << 16);
}
__device__ __forceinline__ float bfhi(unsigned u) {
  return __builtin_bit_cast(float, u & 0xFFFF0000u);
}
__device__ __forceinline__ unsigned long long tagword(unsigned tag, float v) {
  return ((unsigned long long)tag << 32) | (unsigned long long)__builtin_bit_cast(unsigned, v);
}

// ---------------------------------------------------------------------------
// Exchange primitives.
// FAST=true : all 16 WGs of this batch verified co-resident on ONE XCD ->
//             sc0 (L1-bypass) loads + write-through stores are coherent via
//             the shared per-XCD L2 (~200cy) instead of agent-scope ops that
//             round-trip the memory-side coherence point (~900cy).
//             Liveness hedge: every 256 poll iterations fall back to an
//             agent-scope load, so even a wrong cache model cannot hang.
// FAST=false: original agent-scope tagged-word protocol (placement-agnostic).
// ---------------------------------------------------------------------------
template <bool FAST>
__device__ __forceinline__ void gather2(const unsigned long long* p, unsigned tag,
                                        float& f0, float& f1) {
  bool d0 = false, d1 = false;
  int it = 0;
  do {
    unsigned long long a, b;
    if (FAST && ((++it) & 255)) {
      asm volatile("global_load_dwordx2 %0, %2, off sc0\n\t"
                   "global_load_dwordx2 %1, %2, off offset:8 sc0\n\t"
                   "s_waitcnt vmcnt(0)"
                   : "=&v"(a), "=&v"(b)
                   : "v"(p)
                   : "memory");
    } else {
      a = __hip_atomic_load(p, __ATOMIC_RELAXED, __HIP_MEMORY_SCOPE_AGENT);
      b = __hip_atomic_load(p + 1, __ATOMIC_RELAXED, __HIP_MEMORY_SCOPE_AGENT);
    }
    if (!d0 && (unsigned)(a >> 32) == tag) { f0 = __builtin_bit_cast(float, (unsigned)a); d0 = true; }
    if (!d1 && (unsigned)(b >> 32) == tag) { f1 = __builtin_bit_cast(float, (unsigned)b); d1 = true; }
  } while (!(d0 && d1));
}

template <bool FAST>
__device__ __forceinline__ void publish(unsigned long long* p, unsigned long long v) {
  if (FAST) {
    asm volatile("global_store_dwordx2 %0, %1, off sc0" :: "v"(p), "v"(v) : "memory");
  } else {
    __hip_atomic_store(p, v, __ATOMIC_RELAXED, __HIP_MEMORY_SCOPE_AGENT);
  }
}

// ---------------------------------------------------------------------------
// init: zero the tagged exchange arrays (tag 0 == initial state h=0) and the
// XCD claim counters (claim[0..7]=per-XCD slot count, claim[8]=grid barrier)
// ---------------------------------------------------------------------------
__global__ void init_state(unsigned long long* H8, unsigned long long* V8, int* claim) {
  int tid = threadIdx.x;
  for (int i = tid; i < B_ * DH; i += 256) { H8[i] = 0ULL; V8[i] = 0ULL; }
  if (tid < 16) claim[tid] = 0;
}

// ---------------------------------------------------------------------------
// pack x-side gate weights into Wp[1536][512] bf16 (K-major B operand)
// ---------------------------------------------------------------------------
__global__ void pack_w(const float* __restrict__ Wz, const float* __restrict__ Wr,
                       const float* __restrict__ Wh, unsigned short* __restrict__ Wp) {
  int id = blockIdx.x * blockDim.x + threadIdx.x;
  if (id >= NG3 * DH) return;
  int n = id >> 9, k = id & 511;
  float v;
  if (n < 512)       v = Wz[(size_t)n * 1024 + k];
  else if (n < 1024) v = Wr[(size_t)(n - 512) * 1024 + k];
  else               v = Wh[(size_t)(n - 1024) * 1024 + k];
  Wp[id] = f2bf(v);
}

// ---------------------------------------------------------------------------
// GEMM1: seq[32768][512] (bf16) = X[32768][2048] (f32->bf16) @ Wlm[512][2048]^T
// ---------------------------------------------------------------------------
__global__ __launch_bounds__(256) void gemm1_kernel(
    const float* __restrict__ X, const float* __restrict__ Wlm,
    unsigned short* __restrict__ seqb) {
  __shared__ __align__(16) unsigned short sA[64 * 32];
  __shared__ __align__(16) unsigned short sB[64 * 32];
  const int tid = threadIdx.x;
  const int m0 = blockIdx.x * 64, n0 = blockIdx.y * 64;
  const int lrow = tid >> 2, lpart = tid & 3;
  const int w = tid >> 6, lane = tid & 63;
  const int wm = (w >> 1) * 32, wn = (w & 1) * 32;
  const int l16 = lane & 15, quad = lane >> 4;
  f32x4 acc00 = {0.f, 0.f, 0.f, 0.f}, acc01 = {0.f, 0.f, 0.f, 0.f};
  f32x4 acc10 = {0.f, 0.f, 0.f, 0.f}, acc11 = {0.f, 0.f, 0.f, 0.f};
  const float* ap = X + (size_t)(m0 + lrow) * DIN + lpart * 8;
  const float* bp = Wlm + (size_t)(n0 + lrow) * DIN + lpart * 8;
  for (int k0 = 0; k0 < DIN; k0 += 32) {
    float4 a1 = *(const float4*)(ap + k0);
    float4 a2 = *(const float4*)(ap + k0 + 4);
    float4 b1 = *(const float4*)(bp + k0);
    float4 b2 = *(const float4*)(bp + k0 + 4);
    uint4 pa, pb;
    pa.x = f2bf(a1.x) | ((unsigned)f2bf(a1.y) << 16);
    pa.y = f2bf(a1.z) | ((unsigned)f2bf(a1.w) << 16);
    pa.z = f2bf(a2.x) | ((unsigned)f2bf(a2.y) << 16);
    pa.w = f2bf(a2.z) | ((unsigned)f2bf(a2.w) << 16);
    pb.x = f2bf(b1.x) | ((unsigned)f2bf(b1.y) << 16);
    pb.y = f2bf(b1.z) | ((unsigned)f2bf(b1.w) << 16);
    pb.z = f2bf(b2.x) | ((unsigned)f2bf(b2.y) << 16);
    pb.w = f2bf(b2.z) | ((unsigned)f2bf(b2.w) << 16);
    __syncthreads();
    *(uint4*)(sA + lrow * 32 + lpart * 8) = pa;
    *(uint4*)(sB + lrow * 32 + lpart * 8) = pb;
    __syncthreads();
    uint4 ua0 = *(const uint4*)(sA + (wm + l16) * 32 + quad * 8);
    uint4 ua1 = *(const uint4*)(sA + (wm + 16 + l16) * 32 + quad * 8);
    uint4 ub0 = *(const uint4*)(sB + (wn + l16) * 32 + quad * 8);
    uint4 ub1 = *(const uint4*)(sB + (wn + 16 + l16) * 32 + quad * 8);
    bf16x8 a0 = __builtin_bit_cast(bf16x8, ua0);
    bf16x8 a1f = __builtin_bit_cast(bf16x8, ua1);
    bf16x8 b0 = __builtin_bit_cast(bf16x8, ub0);
    bf16x8 b1f = __builtin_bit_cast(bf16x8, ub1);
    acc00 = __builtin_amdgcn_mfma_f32_16x16x32_bf16(a0, b0, acc00, 0, 0, 0);
    acc01 = __builtin_amdgcn_mfma_f32_16x16x32_bf16(a0, b1f, acc01, 0, 0, 0);
    acc10 = __builtin_amdgcn_mfma_f32_16x16x32_bf16(a1f, b0, acc10, 0, 0, 0);
    acc11 = __builtin_amdgcn_mfma_f32_16x16x32_bf16(a1f, b1f, acc11, 0, 0, 0);
  }
#pragma unroll
  for (int r = 0; r < 4; ++r) {
    int row0 = m0 + wm + quad * 4 + r;
    int row1 = row0 + 16;
    int col0 = n0 + wn + l16;
    seqb[(size_t)row0 * DH + col0] = f2bf(acc00[r]);
    seqb[(size_t)row0 * DH + col0 + 16] = f2bf(acc01[r]);
    seqb[(size_t)row1 * DH + col0] = f2bf(acc10[r]);
    seqb[(size_t)row1 * DH + col0 + 16] = f2bf(acc11[r]);
  }
}

// ---------------------------------------------------------------------------
// GEMM2: G[32768][1536] (bf16) = seq[32768][512] (bf16) @ Wp[1536][512]^T
// ---------------------------------------------------------------------------
__global__ __launch_bounds__(256) void gemm2_kernel(
    const unsigned short* __restrict__ Ab, const unsigned short* __restrict__ Bb,
    unsigned short* __restrict__ Cb) {
  __shared__ __align__(16) unsigned short sA[64 * 32];
  __shared__ __align__(16) unsigned short sB[64 * 32];
  const int tid = threadIdx.x;
  const int m0 = blockIdx.x * 64, n0 = blockIdx.y * 64;
  const int lrow = tid >> 2, lpart = tid & 3;
  const int w = tid >> 6, lane = tid & 63;
  const int wm = (w >> 1) * 32, wn = (w & 1) * 32;
  const int l16 = lane & 15, quad = lane >> 4;
  f32x4 acc00 = {0.f, 0.f, 0.f, 0.f}, acc01 = {0.f, 0.f, 0.f, 0.f};
  f32x4 acc10 = {0.f, 0.f, 0.f, 0.f}, acc11 = {0.f, 0.f, 0.f, 0.f};
  const unsigned short* ap = Ab + (size_t)(m0 + lrow) * DH + lpart * 8;
  const unsigned short* bp = Bb + (size_t)(n0 + lrow) * DH + lpart * 8;
  for (int k0 = 0; k0 < DH; k0 += 32) {
    uint4 pa = *(const uint4*)(ap + k0);
    uint4 pb = *(const uint4*)(bp + k0);
    __syncthreads();
    *(uint4*)(sA + lrow * 32 + lpart * 8) = pa;
    *(uint4*)(sB + lrow * 32 + lpart * 8) = pb;
    __syncthreads();
    uint4 ua0 = *(const uint4*)(sA + (wm + l16) * 32 + quad * 8);
    uint4 ua1 = *(const uint4*)(sA + (wm + 16 + l16) * 32 + quad * 8);
    uint4 ub0 = *(const uint4*)(sB + (wn + l16) * 32 + quad * 8);
    uint4 ub1 = *(const uint4*)(sB + (wn + 16 + l16) * 32 + quad * 8);
    bf16x8 a0 = __builtin_bit_cast(bf16x8, ua0);
    bf16x8 a1f = __builtin_bit_cast(bf16x8, ua1);
    bf16x8 b0 = __builtin_bit_cast(bf16x8, ub0);
    bf16x8 b1f = __builtin_bit_cast(bf16x8, ub1);
    acc00 = __builtin_amdgcn_mfma_f32_16x16x32_bf16(a0, b0, acc00, 0, 0, 0);
    acc01 = __builtin_amdgcn_mfma_f32_16x16x32_bf16(a0, b1f, acc01, 0, 0, 0);
    acc10 = __builtin_amdgcn_mfma_f32_16x16x32_bf16(a1f, b0, acc10, 0, 0, 0);
    acc11 = __builtin_amdgcn_mfma_f32_16x16x32_bf16(a1f, b1f, acc11, 0, 0, 0);
  }
#pragma unroll
  for (int r = 0; r < 4; ++r) {
    int row0 = m0 + wm + quad * 4 + r;
    int row1 = row0 + 16;
    int col0 = n0 + wn + l16;
    Cb[(size_t)row0 * NG3 + col0] = f2bf(acc00[r]);
    Cb[(size_t)row0 * NG3 + col0 + 16] = f2bf(acc01[r]);
    Cb[(size_t)row1 * NG3 + col0] = f2bf(acc10[r]);
    Cb[(size_t)row1 * NG3 + col0 + 16] = f2bf(acc11[r]);
  }
}

// ---------------------------------------------------------------------------
// GRU scan t-loop. Tag-chain protocol unchanged (proof in previous session:
// V-gather(t+1) of every WG precedes any H-publish(t+1); H-gather(t) precedes
// any V-publish(t+2) -> no word is overwritten before all readers consume it).
// LDS weight layout: row stride 256 uints, 16B chunks XOR-swizzled by row&7;
// phase A lane (row,p) iter j reads chunk 4j+p, phase B chunk 8j+p ->
// exactly 8 lanes per bank-quad per ds_read_b128 (the wave64 floor; was 8-way
// conflicted with the old part*64 layout + WSTRIDE 260).
// ---------------------------------------------------------------------------
template <bool FAST>
__device__ __forceinline__ void scan_loop(
    const unsigned short* __restrict__ Gb, const unsigned* sWZR, const unsigned* sWH,
    float* hbuf, float* vbuf, float* gz, float* gr, float* gh, float* zb,
    unsigned long long* H8b, unsigned long long* V8b, int rbase, int tid) {
  const int rgA = tid >> 2, gateA = rgA >> 5, rowA = rgA & 31, part4 = tid & 3;
  const int rowB = tid >> 3, part8 = tid & 7;
  const unsigned* wrowA = sWZR + (gateA * ROWS + rowA) * 256;
  const unsigned* wrowB = sWH + rowB * 256;
  const int rxA = rowA & 7, rxB = rowB & 7;

  for (int t = 0; t < S_; ++t) {
    // prefetch this step's gate biases (overlaps the h poll)
    float gval = 0.f;
    if (tid < 96) {
      int gate = tid >> 5, i = tid & 31;
      gval = bf2f(Gb[(size_t)t * NG3 + gate * 512 + rbase + i]);
    }
    // ---- gather h^(t): poll tagged words (tag == t) ----
    {
      float f0, f1;
      gather2<FAST>(H8b + 2 * tid, (unsigned)t, f0, f1);
      hbuf[2 * tid] = f0;
      hbuf[2 * tid + 1] = f1;
    }
    if (tid < 32) gz[tid] = gval;
    else if (tid < 64) gr[tid - 32] = gval;
    else if (tid < 96) gh[tid - 64] = gval;
    __syncthreads();

    // ---- phase A: z and r rows; publish v = r (.) h (tag t+1) ----
    {
      float s = 0.f;
#pragma unroll
      for (int j = 0; j < 16; ++j) {
        int c = j * 4 + part4;                       // chunk = 8 cols
        uint4 w4 = *(const uint4*)(wrowA + ((c ^ rxA) << 2));
        const float* hcp = hbuf + (c << 3);
        float4 h0 = *(const float4*)hcp;
        float4 h1 = *(const float4*)(hcp + 4);
        s += bflo(w4.x) * h0.x + bfhi(w4.x) * h0.y;
        s += bflo(w4.y) * h0.z + bfhi(w4.y) * h0.w;
        s += bflo(w4.z) * h1.x + bfhi(w4.z) * h1.y;
        s += bflo(w4.w) * h1.z + bfhi(w4.w) * h1.w;
      }
      s += __shfl_xor(s, 1);
      s += __shfl_xor(s, 2);
      float a = (gateA ? gr[rowA] : gz[rowA]) + s;
      float act = 1.f / (1.f + expf(-a));
      if (part4 == 0) {
        if (gateA == 0) {
          zb[rowA] = act;
        } else {
          float v = act * hbuf[rbase + rowA];
          publish<FAST>(V8b + rbase + rowA, tagword((unsigned)(t + 1), v));
        }
      }
    }
    // ---- gather v (tag t+1) ----
    {
      float f0, f1;
      gather2<FAST>(V8b + 2 * tid, (unsigned)(t + 1), f0, f1);
      vbuf[2 * tid] = f0;
      vbuf[2 * tid + 1] = f1;
    }
    __syncthreads();   // vbuf + zb ready

    // ---- phase B: h' rows, combine, publish h_new (tag t+1) ----
    {
      float s2 = 0.f;
#pragma unroll
      for (int j = 0; j < 8; ++j) {
        int c = j * 8 + part8;
        uint4 w4 = *(const uint4*)(wrowB + ((c ^ rxB) << 2));
        const float* vcp = vbuf + (c << 3);
        float4 v0 = *(const float4*)vcp;
        float4 v1 = *(const float4*)(vcp + 4);
        s2 += bflo(w4.x) * v0.x + bfhi(w4.x) * v0.y;
        s2 += bflo(w4.y) * v0.z + bfhi(w4.y) * v0.w;
        s2 += bflo(w4.z) * v1.x + bfhi(w4.z) * v1.y;
        s2 += bflo(w4.w) * v1.z + bfhi(w4.w) * v1.w;
      }
      s2 += __shfl_xor(s2, 1);
      s2 += __shfl_xor(s2, 2);
      s2 += __shfl_xor(s2, 4);
      float hp = tanhf(gh[rowB] + s2);
      float z = zb[rowB];
      float hold = hbuf[rbase + rowB];
      float hn = (1.f - z) * hold + z * hp;
      if (part8 == 0) {
        publish<FAST>(H8b + rbase + rowB, tagword((unsigned)(t + 1), hn));
      }
    }
    __syncthreads();   // protects hbuf/vbuf/gz..zb before next iteration
  }
}

// ---------------------------------------------------------------------------
// scan kernel: runtime XCD pinning.
// Each WG reads HW_REG_XCC_ID, claims a slot on its XCD, then a grid barrier
// (cooperative launch -> all 128 WGs co-resident) verifies every XCD got
// exactly NG WGs. If yes: batch = xcd, slice = slot, intra-XCD sc0 exchange.
// If no: fall back to blockIdx mapping + agent-scope exchange (correctness
// never depends on dispatch placement).
// ---------------------------------------------------------------------------
__global__ __launch_bounds__(256) void scan_kernel(
    const unsigned short* __restrict__ G, const float* __restrict__ Wz,
    const float* __restrict__ Wr, const float* __restrict__ Wh,
    unsigned long long* __restrict__ H8, unsigned long long* __restrict__ V8,
    int* __restrict__ claim) {
  extern __shared__ char smem[];
  unsigned* sWZR = (unsigned*)smem;                 // 2*32 rows * 256 u -> 65536 B
  unsigned* sWH  = (unsigned*)(smem + 65536);       // 32 rows  * 256 u -> 32768 B
  float* hbuf = (float*)(smem + 98304);             // 512 f
  float* vbuf = (float*)(smem + 100352);            // 512 f
  float* gz   = (float*)(smem + 102400);            // 32 f
  float* gr   = gz + 32;
  float* gh   = gz + 64;
  float* zb   = gz + 96;
  __shared__ int sMeta[3];

  const int tid = threadIdx.x;

  if (tid == 0) {
    unsigned xcd;
    asm volatile("s_getreg_b32 %0, hwreg(HW_REG_XCC_ID, 0, 32)" : "=s"(xcd));
    xcd &= 7u;
    int slot = __hip_atomic_fetch_add(&claim[xcd], 1, __ATOMIC_RELAXED,
                                      __HIP_MEMORY_SCOPE_AGENT);
    // grid barrier: all claims visible before the count check
    __hip_atomic_fetch_add(&claim[8], 1, __ATOMIC_ACQ_REL, __HIP_MEMORY_SCOPE_AGENT);
    while (__hip_atomic_load(&claim[8], __ATOMIC_ACQUIRE, __HIP_MEMORY_SCOPE_AGENT) < NWG) {}
    int ok = 1;
    for (int i = 0; i < 8; ++i)
      ok &= (__hip_atomic_load(&claim[i], __ATOMIC_RELAXED, __HIP_MEMORY_SCOPE_AGENT) == NG);
    sMeta[0] = ok;
    sMeta[1] = ok ? (int)xcd : (int)(blockIdx.x & 7);
    sMeta[2] = ok ? slot : (int)(blockIdx.x >> 3);
  }
  __syncthreads();
  const int fast = sMeta[0];
  const int b = sMeta[1];
  const int slice = sMeta[2];
  const int rbase = slice * ROWS;

  // ---- stage recurrent-weight slices (h-half columns) into LDS as bf16,
  //      16B-chunk XOR-swizzled by row&7 (conflict-free phase A/B reads) ----
  for (int idx = tid; idx < 3 * ROWS * 256; idx += 256) {
    int g = idx >> 13;            // / 8192
    int rem = idx & 8191;
    int row = rem >> 8, cu = rem & 255;
    const float* src = (g == 0 ? Wz : (g == 1 ? Wr : Wh)) +
                       (size_t)(rbase + row) * 1024 + 512 + 2 * cu;
    unsigned u = (unsigned)f2bf(src[0]) | ((unsigned)f2bf(src[1]) << 16);
    int sw = (((cu >> 2) ^ (row & 7)) << 2) | (cu & 3);
    if (g < 2) sWZR[(g * ROWS + row) * 256 + sw] = u;
    else       sWH[row * 256 + sw] = u;
  }

  unsigned long long* H8b = H8 + b * DH;
  unsigned long long* V8b = V8 + b * DH;
  const unsigned short* Gb = G + (size_t)b * S_ * NG3;

  __syncthreads();   // weights staged

  if (fast)
    scan_loop<true>(Gb, sWZR, sWH, hbuf, vbuf, gz, gr, gh, zb, H8b, V8b, rbase, tid);
  else
    scan_loop<false>(Gb, sWZR, sWH, hbuf, vbuf, gz, gr, gh, zb, H8b, V8b, rbase, tid);
}

// ---------------------------------------------------------------------------
// classifier: out[8][10] = h_final @ W_c^T  (h from tagged words, low 32 bits)
// ---------------------------------------------------------------------------
__global__ void classifier_kernel(const unsigned long long* __restrict__ H8,
                                  const float* __restrict__ Wc,
                                  float* __restrict__ out) {
  int tid = threadIdx.x;
  if (tid < 80) {
    int b = tid / 10, c = tid % 10;
    const unsigned long long* h = H8 + b * DH;
    const float* w = Wc + (size_t)c * DH;
    float s = 0.f;
    for (int i = 0; i < DH; ++i) {
      float hv = __builtin_bit_cast(float, (unsigned)h[i]);
      s += hv * w[i];
    }
    out[tid] = s;
  }
}

extern "C" void kernel_launch(void* const* d_in, const int* in_sizes, int n_in,
                              void* d_out, int out_size, void* d_ws, size_t ws_size,
                              hipStream_t stream) {
  const float* X = (const float*)d_in[0];
  const float* Wlm = (const float*)d_in[1];
  const float* Wz = (const float*)d_in[2];
  const float* Wr = (const float*)d_in[3];
  const float* Wh = (const float*)d_in[4];
  const float* Wc = (const float*)d_in[5];
  float* out = (float*)d_out;

  char* ws = (char*)d_ws;
  unsigned short* seqb = (unsigned short*)ws;              // 33,554,432 B
  unsigned short* G = (unsigned short*)(ws + 33554432);    // 100,663,296 B
  unsigned short* Wp = (unsigned short*)(ws + 134217728);  // 1,572,864 B
  unsigned long long* H8 = (unsigned long long*)(ws + 135790592);  // 32 KB
  unsigned long long* V8 = (unsigned long long*)(ws + 135823360);  // 32 KB
  int* claim = (int*)(ws + 135856128);                     // 64 B

  init_state<<<1, 256, 0, stream>>>(H8, V8, claim);
  pack_w<<<768, 1024, 0, stream>>>(Wz, Wr, Wh, Wp);
  gemm1_kernel<<<dim3(512, 8), 256, 0, stream>>>(X, Wlm, seqb);
  gemm2_kernel<<<dim3(512, 24), 256, 0, stream>>>(seqb, Wp, G);

  {
    const int scan_lds = 102912;
    hipFuncSetAttribute((const void*)scan_kernel,
                        hipFuncAttributeMaxDynamicSharedMemorySize, scan_lds);
    const unsigned short* Gc = G;
    int* claimp = claim;
    void* args[] = {(void*)&Gc, (void*)&Wz, (void*)&Wr, (void*)&Wh,
                    (void*)&H8, (void*)&V8, (void*)&claimp};
    hipLaunchCooperativeKernel((const void*)scan_kernel, dim3(NWG), dim3(256),
                               args, scan_lds, stream);
  }
  classifier_kernel<<<1, 128, 0, stream>>>(H8, Wc, out);
}

// Round 2
// 17658.131 us; speedup vs baseline: 15.9815x; 15.9815x over previous
//
#include <hip/hip_runtime.h>
#include <stdint.h>

#define B_ 8
#define S_ 4096
#define DIN 2048
#define DH 512
#define NG3 1536   // 3 gates * DH
#define NG 16      // workgroups per batch element in the scan
#define ROWS 32    // hidden rows owned per scan workgroup (DH/NG)

typedef __attribute__((ext_vector_type(8))) short bf16x8;
typedef __attribute__((ext_vector_type(4))) float f32x4;

__device__ __forceinline__ unsigned short f2bf(float f) {
  unsigned int u = __builtin_bit_cast(unsigned int, f);
  u = u + 0x7FFFu + ((u >> 16) & 1u);   // RNE
  return (unsigned short)(u >> 16);
}
__device__ __forceinline__ float bf2f(unsigned short h) {
  unsigned int u = ((unsigned int)h) << 16;
  return __builtin_bit_cast(float, u);
}
__device__ __forceinline__ float bflo(unsigned u) {
  return __builtin_bit_cast(float, u << 16);
}
__device__ __forceinline__ float bfhi(unsigned u) {
  return __builtin_bit_cast(float, u & 0xFFFF0000u);
}
__device__ __forceinline__ unsigned long long tagword(unsigned tag, float v) {
  return ((unsigned long long)tag << 32) | (unsigned long long)__builtin_bit_cast(unsigned, v);
}

// ---------------------------------------------------------------------------
// init: zero the tagged exchange arrays (tag 0 == initial state h=0, v invalid)
// ---------------------------------------------------------------------------
__global__ void init_state(unsigned long long* H8, unsigned long long* V8) {
  int tid = threadIdx.x;
  for (int i = tid; i < B_ * DH; i += 256) { H8[i] = 0ULL; V8[i] = 0ULL; }
}

// ---------------------------------------------------------------------------
// pack x-side gate weights into Wp[1536][512] bf16 (K-major B operand)
// ---------------------------------------------------------------------------
__global__ void pack_w(const float* __restrict__ Wz, const float* __restrict__ Wr,
                       const float* __restrict__ Wh, unsigned short* __restrict__ Wp) {
  int id = blockIdx.x * blockDim.x + threadIdx.x;
  if (id >= NG3 * DH) return;
  int n = id >> 9, k = id & 511;
  float v;
  if (n < 512)       v = Wz[(size_t)n * 1024 + k];
  else if (n < 1024) v = Wr[(size_t)(n - 512) * 1024 + k];
  else               v = Wh[(size_t)(n - 1024) * 1024 + k];
  Wp[id] = f2bf(v);
}

// ---------------------------------------------------------------------------
// GEMM1: seq[32768][512] (bf16) = X[32768][2048] (f32->bf16) @ Wlm[512][2048]^T
// ---------------------------------------------------------------------------
__global__ __launch_bounds__(256) void gemm1_kernel(
    const float* __restrict__ X, const float* __restrict__ Wlm,
    unsigned short* __restrict__ seqb) {
  __shared__ __align__(16) unsigned short sA[64 * 32];
  __shared__ __align__(16) unsigned short sB[64 * 32];
  const int tid = threadIdx.x;
  const int m0 = blockIdx.x * 64, n0 = blockIdx.y * 64;
  const int lrow = tid >> 2, lpart = tid & 3;
  const int w = tid >> 6, lane = tid & 63;
  const int wm = (w >> 1) * 32, wn = (w & 1) * 32;
  const int l16 = lane & 15, quad = lane >> 4;
  f32x4 acc00 = {0.f, 0.f, 0.f, 0.f}, acc01 = {0.f, 0.f, 0.f, 0.f};
  f32x4 acc10 = {0.f, 0.f, 0.f, 0.f}, acc11 = {0.f, 0.f, 0.f, 0.f};
  const float* ap = X + (size_t)(m0 + lrow) * DIN + lpart * 8;
  const float* bp = Wlm + (size_t)(n0 + lrow) * DIN + lpart * 8;
  for (int k0 = 0; k0 < DIN; k0 += 32) {
    float4 a1 = *(const float4*)(ap + k0);
    float4 a2 = *(const float4*)(ap + k0 + 4);
    float4 b1 = *(const float4*)(bp + k0);
    float4 b2 = *(const float4*)(bp + k0 + 4);
    uint4 pa, pb;
    pa.x = f2bf(a1.x) | ((unsigned)f2bf(a1.y) << 16);
    pa.y = f2bf(a1.z) | ((unsigned)f2bf(a1.w) << 16);
    pa.z = f2bf(a2.x) | ((unsigned)f2bf(a2.y) << 16);
    pa.w = f2bf(a2.z) | ((unsigned)f2bf(a2.w) << 16);
    pb.x = f2bf(b1.x) | ((unsigned)f2bf(b1.y) << 16);
    pb.y = f2bf(b1.z) | ((unsigned)f2bf(b1.w) << 16);
    pb.z = f2bf(b2.x) | ((unsigned)f2bf(b2.y) << 16);
    pb.w = f2bf(b2.z) | ((unsigned)f2bf(b2.w) << 16);
    __syncthreads();
    *(uint4*)(sA + lrow * 32 + lpart * 8) = pa;
    *(uint4*)(sB + lrow * 32 + lpart * 8) = pb;
    __syncthreads();
    uint4 ua0 = *(const uint4*)(sA + (wm + l16) * 32 + quad * 8);
    uint4 ua1 = *(const uint4*)(sA + (wm + 16 + l16) * 32 + quad * 8);
    uint4 ub0 = *(const uint4*)(sB + (wn + l16) * 32 + quad * 8);
    uint4 ub1 = *(const uint4*)(sB + (wn + 16 + l16) * 32 + quad * 8);
    bf16x8 a0 = __builtin_bit_cast(bf16x8, ua0);
    bf16x8 a1f = __builtin_bit_cast(bf16x8, ua1);
    bf16x8 b0 = __builtin_bit_cast(bf16x8, ub0);
    bf16x8 b1f = __builtin_bit_cast(bf16x8, ub1);
    acc00 = __builtin_amdgcn_mfma_f32_16x16x32_bf16(a0, b0, acc00, 0, 0, 0);
    acc01 = __builtin_amdgcn_mfma_f32_16x16x32_bf16(a0, b1f, acc01, 0, 0, 0);
    acc10 = __builtin_amdgcn_mfma_f32_16x16x32_bf16(a1f, b0, acc10, 0, 0, 0);
    acc11 = __builtin_amdgcn_mfma_f32_16x16x32_bf16(a1f, b1f, acc11, 0, 0, 0);
  }
#pragma unroll
  for (int r = 0; r < 4; ++r) {
    int row0 = m0 + wm + quad * 4 + r;
    int row1 = row0 + 16;
    int col0 = n0 + wn + l16;
    seqb[(size_t)row0 * DH + col0] = f2bf(acc00[r]);
    seqb[(size_t)row0 * DH + col0 + 16] = f2bf(acc01[r]);
    seqb[(size_t)row1 * DH + col0] = f2bf(acc10[r]);
    seqb[(size_t)row1 * DH + col0 + 16] = f2bf(acc11[r]);
  }
}

// ---------------------------------------------------------------------------
// GEMM2: G[32768][1536] (bf16) = seq[32768][512] (bf16) @ Wp[1536][512]^T
// ---------------------------------------------------------------------------
__global__ __launch_bounds__(256) void gemm2_kernel(
    const unsigned short* __restrict__ Ab, const unsigned short* __restrict__ Bb,
    unsigned short* __restrict__ Cb) {
  __shared__ __align__(16) unsigned short sA[64 * 32];
  __shared__ __align__(16) unsigned short sB[64 * 32];
  const int tid = threadIdx.x;
  const int m0 = blockIdx.x * 64, n0 = blockIdx.y * 64;
  const int lrow = tid >> 2, lpart = tid & 3;
  const int w = tid >> 6, lane = tid & 63;
  const int wm = (w >> 1) * 32, wn = (w & 1) * 32;
  const int l16 = lane & 15, quad = lane >> 4;
  f32x4 acc00 = {0.f, 0.f, 0.f, 0.f}, acc01 = {0.f, 0.f, 0.f, 0.f};
  f32x4 acc10 = {0.f, 0.f, 0.f, 0.f}, acc11 = {0.f, 0.f, 0.f, 0.f};
  const unsigned short* ap = Ab + (size_t)(m0 + lrow) * DH + lpart * 8;
  const unsigned short* bp = Bb + (size_t)(n0 + lrow) * DH + lpart * 8;
  for (int k0 = 0; k0 < DH; k0 += 32) {
    uint4 pa = *(const uint4*)(ap + k0);
    uint4 pb = *(const uint4*)(bp + k0);
    __syncthreads();
    *(uint4*)(sA + lrow * 32 + lpart * 8) = pa;
    *(uint4*)(sB + lrow * 32 + lpart * 8) = pb;
    __syncthreads();
    uint4 ua0 = *(const uint4*)(sA + (wm + l16) * 32 + quad * 8);
    uint4 ua1 = *(const uint4*)(sA + (wm + 16 + l16) * 32 + quad * 8);
    uint4 ub0 = *(const uint4*)(sB + (wn + l16) * 32 + quad * 8);
    uint4 ub1 = *(const uint4*)(sB + (wn + 16 + l16) * 32 + quad * 8);
    bf16x8 a0 = __builtin_bit_cast(bf16x8, ua0);
    bf16x8 a1f = __builtin_bit_cast(bf16x8, ua1);
    bf16x8 b0 = __builtin_bit_cast(bf16x8, ub0);
    bf16x8 b1f = __builtin_bit_cast(bf16x8, ub1);
    acc00 = __builtin_amdgcn_mfma_f32_16x16x32_bf16(a0, b0, acc00, 0, 0, 0);
    acc01 = __builtin_amdgcn_mfma_f32_16x16x32_bf16(a0, b1f, acc01, 0, 0, 0);
    acc10 = __builtin_amdgcn_mfma_f32_16x16x32_bf16(a1f, b0, acc10, 0, 0, 0);
    acc11 = __builtin_amdgcn_mfma_f32_16x16x32_bf16(a1f, b1f, acc11, 0, 0, 0);
  }
#pragma unroll
  for (int r = 0; r < 4; ++r) {
    int row0 = m0 + wm + quad * 4 + r;
    int row1 = row0 + 16;
    int col0 = n0 + wn + l16;
    Cb[(size_t)row0 * NG3 + col0] = f2bf(acc00[r]);
    Cb[(size_t)row0 * NG3 + col0 + 16] = f2bf(acc01[r]);
    Cb[(size_t)row1 * NG3 + col0] = f2bf(acc10[r]);
    Cb[(size_t)row1 * NG3 + col0 + 16] = f2bf(acc11[r]);
  }
}

// ---------------------------------------------------------------------------
// GRU scan — tagged-word exchange (agent scope, proven), NO fences/counters.
// H8/V8: one ulong per hidden element: hi32 = step tag, lo32 = fp32 value.
// A word with tag T is only overwritten after every reader consumed tag T
// (tag chain forms the barrier — see Round-0 proof).
//
// LDS weight layout (Round-1 verified fix, SQ_LDS_BANK_CONFLICT 2.23e9->1.7e7):
// row stride 256 uints, 16B chunks XOR-swizzled by row&7; phase A lane
// (row,p) iter j reads chunk 4j+p, phase B chunk 8j+p -> exactly 8 lanes per
// bank-quad per ds_read_b128 (the wave64 floor).
// ---------------------------------------------------------------------------
__global__ __launch_bounds__(256) void scan_kernel(
    const unsigned short* __restrict__ G, const float* __restrict__ Wz,
    const float* __restrict__ Wr, const float* __restrict__ Wh,
    unsigned long long* __restrict__ H8, unsigned long long* __restrict__ V8) {
  extern __shared__ char smem[];
  unsigned* sWZR = (unsigned*)smem;                 // 2*32 rows * 256 u -> 65536 B
  unsigned* sWH  = (unsigned*)(smem + 65536);       // 32 rows  * 256 u -> 32768 B
  float* hbuf = (float*)(smem + 98304);             // 512 f
  float* vbuf = (float*)(smem + 100352);            // 512 f
  float* gz   = (float*)(smem + 102400);            // 32 f
  float* gr   = gz + 32;
  float* gh   = gz + 64;
  float* zb   = gz + 96;

  const int tid = threadIdx.x;
  const int wg = blockIdx.x;
  const int b = wg & 7;
  const int slice = wg >> 3;
  const int rbase = slice * ROWS;

  // ---- stage recurrent-weight slices (h-half columns) into LDS as bf16,
  //      16B-chunk XOR-swizzled by row&7 ----
  for (int idx = tid; idx < 3 * ROWS * 256; idx += 256) {
    int g = idx >> 13;            // / 8192
    int rem = idx & 8191;
    int row = rem >> 8, cu = rem & 255;
    const float* src = (g == 0 ? Wz : (g == 1 ? Wr : Wh)) +
                       (size_t)(rbase + row) * 1024 + 512 + 2 * cu;
    unsigned u = (unsigned)f2bf(src[0]) | ((unsigned)f2bf(src[1]) << 16);
    int sw = (((cu >> 2) ^ (row & 7)) << 2) | (cu & 3);
    if (g < 2) sWZR[(g * ROWS + row) * 256 + sw] = u;
    else       sWH[row * 256 + sw] = u;
  }

  // phase A mapping: (gate z/r, row, 4 lanes x 16 chunks)
  const int rgA = tid >> 2, gateA = rgA >> 5, rowA = rgA & 31, part4 = tid & 3;
  // phase B mapping: (row, 8 lanes x 8 chunks)
  const int rowB = tid >> 3, part8 = tid & 7;
  const unsigned* wrowA = sWZR + (gateA * ROWS + rowA) * 256;
  const unsigned* wrowB = sWH + rowB * 256;
  const int rxA = rowA & 7, rxB = rowB & 7;

  unsigned long long* H8b = H8 + b * DH;
  unsigned long long* V8b = V8 + b * DH;
  const unsigned short* Gb = G + (size_t)b * S_ * NG3;

  __syncthreads();   // weights staged

  for (int t = 0; t < S_; ++t) {
    // prefetch this step's gate biases (overlaps the h poll)
    float gval = 0.f;
    if (tid < 96) {
      int gate = tid >> 5, i = tid & 31;
      gval = bf2f(Gb[(size_t)t * NG3 + gate * 512 + rbase + i]);
    }
    // ---- gather h^(t): poll tagged words (tag == t) ----
    {
      const unsigned tagH = (unsigned)t;
      unsigned long long* p0 = H8b + 2 * tid;
      float f0, f1;
      bool d0 = false, d1 = false;
      do {
        if (!d0) {
          unsigned long long w = __hip_atomic_load(p0, __ATOMIC_RELAXED, __HIP_MEMORY_SCOPE_AGENT);
          if ((unsigned)(w >> 32) == tagH) { f0 = __builtin_bit_cast(float, (unsigned)w); d0 = true; }
        }
        if (!d1) {
          unsigned long long w = __hip_atomic_load(p0 + 1, __ATOMIC_RELAXED, __HIP_MEMORY_SCOPE_AGENT);
          if ((unsigned)(w >> 32) == tagH) { f1 = __builtin_bit_cast(float, (unsigned)w); d1 = true; }
        }
      } while (!(d0 && d1));
      hbuf[2 * tid] = f0;
      hbuf[2 * tid + 1] = f1;
    }
    if (tid < 32) gz[tid] = gval;
    else if (tid < 64) gr[tid - 32] = gval;
    else if (tid < 96) gh[tid - 64] = gval;
    __syncthreads();

    // ---- phase A: z and r rows; publish v = r (.) h (tag t+1) ----
    {
      float s = 0.f;
#pragma unroll
      for (int j = 0; j < 16; ++j) {
        int c = j * 4 + part4;                       // chunk = 8 cols
        uint4 w4 = *(const uint4*)(wrowA + ((c ^ rxA) << 2));
        const float* hcp = hbuf + (c << 3);
        float4 h0 = *(const float4*)hcp;
        float4 h1 = *(const float4*)(hcp + 4);
        s += bflo(w4.x) * h0.x + bfhi(w4.x) * h0.y;
        s += bflo(w4.y) * h0.z + bfhi(w4.y) * h0.w;
        s += bflo(w4.z) * h1.x + bfhi(w4.z) * h1.y;
        s += bflo(w4.w) * h1.z + bfhi(w4.w) * h1.w;
      }
      s += __shfl_xor(s, 1);
      s += __shfl_xor(s, 2);
      float a = (gateA ? gr[rowA] : gz[rowA]) + s;
      float act = 1.f / (1.f + expf(-a));
      if (part4 == 0) {
        if (gateA == 0) {
          zb[rowA] = act;
        } else {
          float v = act * hbuf[rbase + rowA];
          __hip_atomic_store(V8b + rbase + rowA, tagword((unsigned)(t + 1), v),
                             __ATOMIC_RELAXED, __HIP_MEMORY_SCOPE_AGENT);
        }
      }
    }
    // ---- gather v (tag t+1) ----
    {
      const unsigned tagV = (unsigned)(t + 1);
      unsigned long long* p0 = V8b + 2 * tid;
      float f0, f1;
      bool d0 = false, d1 = false;
      do {
        if (!d0) {
          unsigned long long w = __hip_atomic_load(p0, __ATOMIC_RELAXED, __HIP_MEMORY_SCOPE_AGENT);
          if ((unsigned)(w >> 32) == tagV) { f0 = __builtin_bit_cast(float, (unsigned)w); d0 = true; }
        }
        if (!d1) {
          unsigned long long w = __hip_atomic_load(p0 + 1, __ATOMIC_RELAXED, __HIP_MEMORY_SCOPE_AGENT);
          if ((unsigned)(w >> 32) == tagV) { f1 = __builtin_bit_cast(float, (unsigned)w); d1 = true; }
        }
      } while (!(d0 && d1));
      vbuf[2 * tid] = f0;
      vbuf[2 * tid + 1] = f1;
    }
    __syncthreads();   // vbuf + zb ready

    // ---- phase B: h' rows, combine, publish h_new (tag t+1) ----
    {
      float s2 = 0.f;
#pragma unroll
      for (int j = 0; j < 8; ++j) {
        int c = j * 8 + part8;
        uint4 w4 = *(const uint4*)(wrowB + ((c ^ rxB) << 2));
        const float* vcp = vbuf + (c << 3);
        float4 v0 = *(const float4*)vcp;
        float4 v1 = *(const float4*)(vcp + 4);
        s2 += bflo(w4.x) * v0.x + bfhi(w4.x) * v0.y;
        s2 += bflo(w4.y) * v0.z + bfhi(w4.y) * v0.w;
        s2 += bflo(w4.z) * v1.x + bfhi(w4.z) * v1.y;
        s2 += bflo(w4.w) * v1.z + bfhi(w4.w) * v1.w;
      }
      s2 += __shfl_xor(s2, 1);
      s2 += __shfl_xor(s2, 2);
      s2 += __shfl_xor(s2, 4);
      float hp = tanhf(gh[rowB] + s2);
      float z = zb[rowB];
      float hold = hbuf[rbase + rowB];
      float hn = (1.f - z) * hold + z * hp;
      if (part8 == 0) {
        __hip_atomic_store(H8b + rbase + rowB, tagword((unsigned)(t + 1), hn),
                           __ATOMIC_RELAXED, __HIP_MEMORY_SCOPE_AGENT);
      }
    }
    __syncthreads();   // protects hbuf/vbuf/gz..zb before next iteration
  }
}

// ---------------------------------------------------------------------------
// classifier: out[8][10] = h_final @ W_c^T  (h from tagged words, low 32 bits)
// ---------------------------------------------------------------------------
__global__ void classifier_kernel(const unsigned long long* __restrict__ H8,
                                  const float* __restrict__ Wc,
                                  float* __restrict__ out) {
  int tid = threadIdx.x;
  if (tid < 80) {
    int b = tid / 10, c = tid % 10;
    const unsigned long long* h = H8 + b * DH;
    const float* w = Wc + (size_t)c * DH;
    float s = 0.f;
    for (int i = 0; i < DH; ++i) {
      float hv = __builtin_bit_cast(float, (unsigned)h[i]);
      s += hv * w[i];
    }
    out[tid] = s;
  }
}

extern "C" void kernel_launch(void* const* d_in, const int* in_sizes, int n_in,
                              void* d_out, int out_size, void* d_ws, size_t ws_size,
                              hipStream_t stream) {
  const float* X = (const float*)d_in[0];
  const float* Wlm = (const float*)d_in[1];
  const float* Wz = (const float*)d_in[2];
  const float* Wr = (const float*)d_in[3];
  const float* Wh = (const float*)d_in[4];
  const float* Wc = (const float*)d_in[5];
  float* out = (float*)d_out;

  char* ws = (char*)d_ws;
  unsigned short* seqb = (unsigned short*)ws;              // 33,554,432 B
  unsigned short* G = (unsigned short*)(ws + 33554432);    // 100,663,296 B
  unsigned short* Wp = (unsigned short*)(ws + 134217728);  // 1,572,864 B
  unsigned long long* H8 = (unsigned long long*)(ws + 135790592);  // 32 KB
  unsigned long long* V8 = (unsigned long long*)(ws + 135823360);  // 32 KB

  init_state<<<1, 256, 0, stream>>>(H8, V8);
  pack_w<<<768, 1024, 0, stream>>>(Wz, Wr, Wh, Wp);
  gemm1_kernel<<<dim3(512, 8), 256, 0, stream>>>(X, Wlm, seqb);
  gemm2_kernel<<<dim3(512, 24), 256, 0, stream>>>(seqb, Wp, G);

  {
    const int scan_lds = 102912;
    hipFuncSetAttribute((const void*)scan_kernel,
                        hipFuncAttributeMaxDynamicSharedMemorySize, scan_lds);
    const unsigned short* Gc = G;
    void* args[] = {(void*)&Gc, (void*)&Wz, (void*)&Wr, (void*)&Wh,
                    (void*)&H8, (void*)&V8};
    hipLaunchCooperativeKernel((const void*)scan_kernel, dim3(NG * B_), dim3(256),
                               args, scan_lds, stream);
  }
  classifier_kernel<<<1, 128, 0, stream>>>(H8, Wc, out);
}

// Round 3
// 13800.229 us; speedup vs baseline: 20.4491x; 1.2796x over previous
//
#include <hip/hip_runtime.h>
#include <stdint.h>

#define B_ 8
#define S_ 4096
#define DIN 2048
#define DH 512
#define NG3 1536   // 3 gates * DH
#define NG 16      // workgroups per batch element in the scan
#define ROWS 32    // hidden rows owned per scan workgroup (DH/NG)
#define NWG (NG * B_)

// f64 magnitude-tagged accumulation:
//   each WG adds (partial * 2^20 + 2^40); word complete <=> value >= 15.5*2^40.
// Exact: 2^40 + p*2^20 spans <= 41 binades < 53-bit mantissa; |p|<64 so
// |sum of scaled partials| < 2^30 << 2^39 (no threshold ambiguity).
#define ACC_SCALE    1048576.0              // 2^20
#define ACC_INVSCALE 9.5367431640625e-07    // 2^-20
#define ACC_BIAS     1099511627776.0        // 2^40
#define ACC_FULL     17592186044416.0       // 16 * 2^40
#define ACC_THRESH   17042430230528.0       // 15.5 * 2^40

typedef __attribute__((ext_vector_type(8))) short bf16x8;
typedef __attribute__((ext_vector_type(4))) float f32x4;

__device__ __forceinline__ unsigned short f2bf(float f) {
  unsigned int u = __builtin_bit_cast(unsigned int, f);
  u = u + 0x7FFFu + ((u >> 16) & 1u);   // RNE
  return (unsigned short)(u >> 16);
}
__device__ __forceinline__ float bf2f(unsigned short h) {
  unsigned int u = ((unsigned int)h) << 16;
  return __builtin_bit_cast(float, u);
}
__device__ __forceinline__ float bflo(unsigned u) {
  return __builtin_bit_cast(float, u << 16);
}
__device__ __forceinline__ float bfhi(unsigned u) {
  return __builtin_bit_cast(float, u & 0xFFFF0000u);
}

// ---------------------------------------------------------------------------
// init: zero the 3 rotating accumulator phases (8 batches x 3 x 1024 doubles)
// ---------------------------------------------------------------------------
__global__ void init_state(unsigned long long* ACCu) {
  int id = blockIdx.x * blockDim.x + threadIdx.x;
  if (id < B_ * 3 * 1024) ACCu[id] = 0ULL;
}

// ---------------------------------------------------------------------------
// pack x-side gate weights into Wp[1536][512] bf16 (K-major B operand)
// ---------------------------------------------------------------------------
__global__ void pack_w(const float* __restrict__ Wz, const float* __restrict__ Wr,
                       const float* __restrict__ Wh, unsigned short* __restrict__ Wp) {
  int id = blockIdx.x * blockDim.x + threadIdx.x;
  if (id >= NG3 * DH) return;
  int n = id >> 9, k = id & 511;
  float v;
  if (n < 512)       v = Wz[(size_t)n * 1024 + k];
  else if (n < 1024) v = Wr[(size_t)(n - 512) * 1024 + k];
  else               v = Wh[(size_t)(n - 1024) * 1024 + k];
  Wp[id] = f2bf(v);
}

// ---------------------------------------------------------------------------
// GEMM1: seq[32768][512] (bf16) = X[32768][2048] (f32->bf16) @ Wlm[512][2048]^T
// ---------------------------------------------------------------------------
__global__ __launch_bounds__(256) void gemm1_kernel(
    const float* __restrict__ X, const float* __restrict__ Wlm,
    unsigned short* __restrict__ seqb) {
  __shared__ __align__(16) unsigned short sA[64 * 32];
  __shared__ __align__(16) unsigned short sB[64 * 32];
  const int tid = threadIdx.x;
  const int m0 = blockIdx.x * 64, n0 = blockIdx.y * 64;
  const int lrow = tid >> 2, lpart = tid & 3;
  const int w = tid >> 6, lane = tid & 63;
  const int wm = (w >> 1) * 32, wn = (w & 1) * 32;
  const int l16 = lane & 15, quad = lane >> 4;
  f32x4 acc00 = {0.f, 0.f, 0.f, 0.f}, acc01 = {0.f, 0.f, 0.f, 0.f};
  f32x4 acc10 = {0.f, 0.f, 0.f, 0.f}, acc11 = {0.f, 0.f, 0.f, 0.f};
  const float* ap = X + (size_t)(m0 + lrow) * DIN + lpart * 8;
  const float* bp = Wlm + (size_t)(n0 + lrow) * DIN + lpart * 8;
  for (int k0 = 0; k0 < DIN; k0 += 32) {
    float4 a1 = *(const float4*)(ap + k0);
    float4 a2 = *(const float4*)(ap + k0 + 4);
    float4 b1 = *(const float4*)(bp + k0);
    float4 b2 = *(const float4*)(bp + k0 + 4);
    uint4 pa, pb;
    pa.x = f2bf(a1.x) | ((unsigned)f2bf(a1.y) << 16);
    pa.y = f2bf(a1.z) | ((unsigned)f2bf(a1.w) << 16);
    pa.z = f2bf(a2.x) | ((unsigned)f2bf(a2.y) << 16);
    pa.w = f2bf(a2.z) | ((unsigned)f2bf(a2.w) << 16);
    pb.x = f2bf(b1.x) | ((unsigned)f2bf(b1.y) << 16);
    pb.y = f2bf(b1.z) | ((unsigned)f2bf(b1.w) << 16);
    pb.z = f2bf(b2.x) | ((unsigned)f2bf(b2.y) << 16);
    pb.w = f2bf(b2.z) | ((unsigned)f2bf(b2.w) << 16);
    __syncthreads();
    *(uint4*)(sA + lrow * 32 + lpart * 8) = pa;
    *(uint4*)(sB + lrow * 32 + lpart * 8) = pb;
    __syncthreads();
    uint4 ua0 = *(const uint4*)(sA + (wm + l16) * 32 + quad * 8);
    uint4 ua1 = *(const uint4*)(sA + (wm + 16 + l16) * 32 + quad * 8);
    uint4 ub0 = *(const uint4*)(sB + (wn + l16) * 32 + quad * 8);
    uint4 ub1 = *(const uint4*)(sB + (wn + 16 + l16) * 32 + quad * 8);
    bf16x8 a0 = __builtin_bit_cast(bf16x8, ua0);
    bf16x8 a1f = __builtin_bit_cast(bf16x8, ua1);
    bf16x8 b0 = __builtin_bit_cast(bf16x8, ub0);
    bf16x8 b1f = __builtin_bit_cast(bf16x8, ub1);
    acc00 = __builtin_amdgcn_mfma_f32_16x16x32_bf16(a0, b0, acc00, 0, 0, 0);
    acc01 = __builtin_amdgcn_mfma_f32_16x16x32_bf16(a0, b1f, acc01, 0, 0, 0);
    acc10 = __builtin_amdgcn_mfma_f32_16x16x32_bf16(a1f, b0, acc10, 0, 0, 0);
    acc11 = __builtin_amdgcn_mfma_f32_16x16x32_bf16(a1f, b1f, acc11, 0, 0, 0);
  }
#pragma unroll
  for (int r = 0; r < 4; ++r) {
    int row0 = m0 + wm + quad * 4 + r;
    int row1 = row0 + 16;
    int col0 = n0 + wn + l16;
    seqb[(size_t)row0 * DH + col0] = f2bf(acc00[r]);
    seqb[(size_t)row0 * DH + col0 + 16] = f2bf(acc01[r]);
    seqb[(size_t)row1 * DH + col0] = f2bf(acc10[r]);
    seqb[(size_t)row1 * DH + col0 + 16] = f2bf(acc11[r]);
  }
}

// ---------------------------------------------------------------------------
// GEMM2: G[32768][1536] (bf16) = seq[32768][512] (bf16) @ Wp[1536][512]^T
// ---------------------------------------------------------------------------
__global__ __launch_bounds__(256) void gemm2_kernel(
    const unsigned short* __restrict__ Ab, const unsigned short* __restrict__ Bb,
    unsigned short* __restrict__ Cb) {
  __shared__ __align__(16) unsigned short sA[64 * 32];
  __shared__ __align__(16) unsigned short sB[64 * 32];
  const int tid = threadIdx.x;
  const int m0 = blockIdx.x * 64, n0 = blockIdx.y * 64;
  const int lrow = tid >> 2, lpart = tid & 3;
  const int w = tid >> 6, lane = tid & 63;
  const int wm = (w >> 1) * 32, wn = (w & 1) * 32;
  const int l16 = lane & 15, quad = lane >> 4;
  f32x4 acc00 = {0.f, 0.f, 0.f, 0.f}, acc01 = {0.f, 0.f, 0.f, 0.f};
  f32x4 acc10 = {0.f, 0.f, 0.f, 0.f}, acc11 = {0.f, 0.f, 0.f, 0.f};
  const unsigned short* ap = Ab + (size_t)(m0 + lrow) * DH + lpart * 8;
  const unsigned short* bp = Bb + (size_t)(n0 + lrow) * DH + lpart * 8;
  for (int k0 = 0; k0 < DH; k0 += 32) {
    uint4 pa = *(const uint4*)(ap + k0);
    uint4 pb = *(const uint4*)(bp + k0);
    __syncthreads();
    *(uint4*)(sA + lrow * 32 + lpart * 8) = pa;
    *(uint4*)(sB + lrow * 32 + lpart * 8) = pb;
    __syncthreads();
    uint4 ua0 = *(const uint4*)(sA + (wm + l16) * 32 + quad * 8);
    uint4 ua1 = *(const uint4*)(sA + (wm + 16 + l16) * 32 + quad * 8);
    uint4 ub0 = *(const uint4*)(sB + (wn + l16) * 32 + quad * 8);
    uint4 ub1 = *(const uint4*)(sB + (wn + 16 + l16) * 32 + quad * 8);
    bf16x8 a0 = __builtin_bit_cast(bf16x8, ua0);
    bf16x8 a1f = __builtin_bit_cast(bf16x8, ua1);
    bf16x8 b0 = __builtin_bit_cast(bf16x8, ub0);
    bf16x8 b1f = __builtin_bit_cast(bf16x8, ub1);
    acc00 = __builtin_amdgcn_mfma_f32_16x16x32_bf16(a0, b0, acc00, 0, 0, 0);
    acc01 = __builtin_amdgcn_mfma_f32_16x16x32_bf16(a0, b1f, acc01, 0, 0, 0);
    acc10 = __builtin_amdgcn_mfma_f32_16x16x32_bf16(a1f, b0, acc10, 0, 0, 0);
    acc11 = __builtin_amdgcn_mfma_f32_16x16x32_bf16(a1f, b1f, acc11, 0, 0, 0);
  }
#pragma unroll
  for (int r = 0; r < 4; ++r) {
    int row0 = m0 + wm + quad * 4 + r;
    int row1 = row0 + 16;
    int col0 = n0 + wn + l16;
    Cb[(size_t)row0 * NG3 + col0] = f2bf(acc00[r]);
    Cb[(size_t)row0 * NG3 + col0 + 16] = f2bf(acc01[r]);
    Cb[(size_t)row1 * NG3 + col0] = f2bf(acc10[r]);
    Cb[(size_t)row1 * NG3 + col0 + 16] = f2bf(acc11[r]);
  }
}

// ---------------------------------------------------------------------------
// GRU scan — k-split, ONE exchange hop per step.
//
// WG (b, slice) owns k-indices [rbase, rbase+32).  Per step t:
//   pz partial:  pz[row] += Wz[row][512+k]*h[k]      (k in slice; all 512 rows)
//   r exact:     r[k] = sigm(gr[k] + Wr[k][512+:].h) (full h, local)
//   v local:     v[k] = r[k]*h[k]
//   ph partial:  ph[row] += Wh[row][512+k]*v[k]
//   publish:     f64 atomicAdd of (partial*2^20 + 2^40) into ACC[b][t%3][...]
//   poll:        own 4 words (rows 2t,2t+1 for pz,ph) until >= 15.5*2^40
//   assemble:    full h(t+1) computed redundantly & bitwise-identically per WG.
//
// Phase rotation proof (3 phases, no counters): adds(t)->phase t%3; zero of
// phase (t+2)%3 at step t is gated on poll(t) which requires all adds(t),
// which (program order + barrier vmcnt drain) follow each WG's reads(t-1) of
// that same phase; adds(t+2) to it are gated on poll(t+1) which requires all
// adds(t+1), which follow each WG's zero at t (barrier-drained).  Bounded
// spins guarantee termination even if this reasoning is wrong.
// ---------------------------------------------------------------------------
__global__ __launch_bounds__(256) void scan_kernel(
    const unsigned short* __restrict__ G, const float* __restrict__ Wz,
    const float* __restrict__ Wr, const float* __restrict__ Wh,
    double* __restrict__ ACC, float* __restrict__ Hout) {
  extern __shared__ char smem[];
  unsigned* sWR = (unsigned*)smem;                  // Wr row-slice  [32][256u] 32KB
  unsigned* sZ  = (unsigned*)(smem + 32768);        // Wz col-slice  [256][32u] 32KB
  unsigned* sH  = (unsigned*)(smem + 65536);        // Wh col-slice  [256][32u] 32KB
  float* hbuf = (float*)(smem + 98304);             // 512 f
  float* vbuf = (float*)(smem + 100352);            // 32 f
  float* grbuf = (float*)(smem + 100480);           // 32 f

  const int tid = threadIdx.x;
  const int wg = blockIdx.x;
  const int b = wg & 7;
  const int slice = wg >> 3;
  const int rbase = slice * ROWS;

  // ---- stage Wr row-slice (h-half cols), 16B-chunk XOR swizzle by row&7 ----
  for (int idx = tid; idx < ROWS * 256; idx += 256) {
    int row = idx >> 8, cu = idx & 255;
    const float* src = Wr + (size_t)(rbase + row) * 1024 + 512 + 2 * cu;
    unsigned u = (unsigned)f2bf(src[0]) | ((unsigned)f2bf(src[1]) << 16);
    int sw = (((cu >> 2) ^ (row & 7)) << 2) | (cu & 3);
    sWR[row * 256 + sw] = u;
  }
  // ---- stage Wz/Wh column-slices: uint (row-pair) x 32 k, chunk-swizzled ----
  for (int idx = tid; idx < 8192; idx += 256) {
    int rp = idx >> 5, k = idx & 31;
    size_t col = 512 + rbase + k;
    unsigned uz = (unsigned)f2bf(Wz[(size_t)(2 * rp) * 1024 + col]) |
                  ((unsigned)f2bf(Wz[(size_t)(2 * rp + 1) * 1024 + col]) << 16);
    unsigned uh = (unsigned)f2bf(Wh[(size_t)(2 * rp) * 1024 + col]) |
                  ((unsigned)f2bf(Wh[(size_t)(2 * rp + 1) * 1024 + col]) << 16);
    int sw = rp * 32 + ((((k >> 2) ^ (rp & 7)) << 2) | (k & 3));
    sZ[sw] = uz;
    sH[sw] = uh;
  }
  // h(0) = 0
  hbuf[2 * tid] = 0.f;
  hbuf[2 * tid + 1] = 0.f;

  const unsigned short* Gb = G + (size_t)b * S_ * NG3;
  double* ACCb = ACC + (size_t)b * 3 * 1024;
  const int tx = tid & 7;
  const int rowB = tid >> 3, part8 = tid & 7, rx = rowB & 7;
  const unsigned* wrow = sWR + rowB * 256;
  const unsigned* zrow = sZ + tid * 32;
  const unsigned* hrow = sH + tid * 32;

  // preload G(0)
  unsigned gzu = *(const unsigned*)(Gb + 2 * tid);
  unsigned ghu = *(const unsigned*)(Gb + 1024 + 2 * tid);
  if (tid < 16) {
    unsigned g = *(const unsigned*)(Gb + 512 + rbase + 2 * tid);
    grbuf[2 * tid] = bflo(g);
    grbuf[2 * tid + 1] = bfhi(g);
  }
  long long spin_budget = 1LL << 22;   // hang guard (never hit when correct)

  __syncthreads();   // weights + hbuf + grbuf staged

  for (int t = 0; t < S_; ++t) {
    double* ACCp = ACCb + (t % 3) * 1024;

    // ---- own-slice h into regs (broadcast LDS reads) ----
    float4 hown[8];
#pragma unroll
    for (int c = 0; c < 8; ++c) hown[c] = *(const float4*)(hbuf + rbase + 4 * c);

    // ---- pz partial for rows 2tid, 2tid+1; publish early ----
    {
      float p0 = 0.f, p1 = 0.f;
#pragma unroll
      for (int c = 0; c < 8; ++c) {
        uint4 w4 = *(const uint4*)(zrow + ((c ^ tx) << 2));
        float4 hk = hown[c];
        p0 += bflo(w4.x) * hk.x; p1 += bfhi(w4.x) * hk.x;
        p0 += bflo(w4.y) * hk.y; p1 += bfhi(w4.y) * hk.y;
        p0 += bflo(w4.z) * hk.z; p1 += bfhi(w4.z) * hk.z;
        p0 += bflo(w4.w) * hk.w; p1 += bfhi(w4.w) * hk.w;
      }
      unsafeAtomicAdd(ACCp + 2 * tid, (double)p0 * ACC_SCALE + ACC_BIAS);
      unsafeAtomicAdd(ACCp + 2 * tid + 1, (double)p1 * ACC_SCALE + ACC_BIAS);
    }

    // ---- r exact for own k = rbase+rowB (full h); v local ----
    {
      float s = 0.f;
#pragma unroll
      for (int j = 0; j < 8; ++j) {
        int c = j * 8 + part8;
        uint4 w4 = *(const uint4*)(wrow + ((c ^ rx) << 2));
        const float* hcp = hbuf + (c << 3);
        float4 h0 = *(const float4*)hcp;
        float4 h1 = *(const float4*)(hcp + 4);
        s += bflo(w4.x) * h0.x + bfhi(w4.x) * h0.y;
        s += bflo(w4.y) * h0.z + bfhi(w4.y) * h0.w;
        s += bflo(w4.z) * h1.x + bfhi(w4.z) * h1.y;
        s += bflo(w4.w) * h1.z + bfhi(w4.w) * h1.w;
      }
      s += __shfl_xor(s, 1);
      s += __shfl_xor(s, 2);
      s += __shfl_xor(s, 4);
      if (part8 == 0) {
        float r = 1.f / (1.f + expf(-(grbuf[rowB] + s)));
        vbuf[rowB] = r * hbuf[rbase + rowB];
      }
    }
    __syncthreads();   // barrier 1: vbuf ready; all hbuf reads done

    // ---- ph partial; publish ----
    {
      float4 vown[8];
#pragma unroll
      for (int c = 0; c < 8; ++c) vown[c] = *(const float4*)(vbuf + 4 * c);
      float p0 = 0.f, p1 = 0.f;
#pragma unroll
      for (int c = 0; c < 8; ++c) {
        uint4 w4 = *(const uint4*)(hrow + ((c ^ tx) << 2));
        float4 vk = vown[c];
        p0 += bflo(w4.x) * vk.x; p1 += bfhi(w4.x) * vk.x;
        p0 += bflo(w4.y) * vk.y; p1 += bfhi(w4.y) * vk.y;
        p0 += bflo(w4.z) * vk.z; p1 += bfhi(w4.z) * vk.z;
        p0 += bflo(w4.w) * vk.w; p1 += bfhi(w4.w) * vk.w;
      }
      unsafeAtomicAdd(ACCp + 512 + 2 * tid, (double)p0 * ACC_SCALE + ACC_BIAS);
      unsafeAtomicAdd(ACCp + 512 + 2 * tid + 1, (double)p1 * ACC_SCALE + ACC_BIAS);
    }

    // ---- prefetch G(t+1) (overlaps the poll) ----
    unsigned gzu2 = gzu, ghu2 = ghu, gru2 = 0;
    if (t + 1 < S_) {
      const unsigned short* Gt = Gb + (size_t)(t + 1) * NG3;
      gzu2 = *(const unsigned*)(Gt + 2 * tid);
      ghu2 = *(const unsigned*)(Gt + 1024 + 2 * tid);
      if (tid < 16) gru2 = *(const unsigned*)(Gt + 512 + rbase + 2 * tid);
    }

    // ---- poll own 4 words (the poll IS the data read) ----
    double dz0, dz1, dh0, dh1;
    {
      const unsigned long long* pz0p = (const unsigned long long*)(ACCp + 2 * tid);
      const unsigned long long* ph0p = (const unsigned long long*)(ACCp + 512 + 2 * tid);
      bool d0 = false, d1 = false, d2 = false, d3 = false;
      do {
        if (!d0) {
          double x = __builtin_bit_cast(double, __hip_atomic_load(pz0p, __ATOMIC_RELAXED, __HIP_MEMORY_SCOPE_AGENT));
          if (x >= ACC_THRESH) { dz0 = x; d0 = true; }
        }
        if (!d1) {
          double x = __builtin_bit_cast(double, __hip_atomic_load(pz0p + 1, __ATOMIC_RELAXED, __HIP_MEMORY_SCOPE_AGENT));
          if (x >= ACC_THRESH) { dz1 = x; d1 = true; }
        }
        if (!d2) {
          double x = __builtin_bit_cast(double, __hip_atomic_load(ph0p, __ATOMIC_RELAXED, __HIP_MEMORY_SCOPE_AGENT));
          if (x >= ACC_THRESH) { dh0 = x; d2 = true; }
        }
        if (!d3) {
          double x = __builtin_bit_cast(double, __hip_atomic_load(ph0p + 1, __ATOMIC_RELAXED, __HIP_MEMORY_SCOPE_AGENT));
          if (x >= ACC_THRESH) { dh1 = x; d3 = true; }
        }
      } while (!(d0 && d1 && d2 && d3) && --spin_budget > 0);
      if (spin_budget <= 0) { dz0 = dz1 = dh0 = dh1 = ACC_FULL; }  // fail-safe
    }

    // ---- zero phase (t+2)%3 (gated on this WG's poll; see proof above) ----
    {
      int q = (t + 2) % 3;
      if (tid < 64)
        __hip_atomic_store((unsigned long long*)(ACCb + q * 1024 + slice * 64 + tid),
                           0ULL, __ATOMIC_RELAXED, __HIP_MEMORY_SCOPE_AGENT);
    }

    // ---- assemble h(t+1) rows 2tid, 2tid+1 (identical math in every WG) ----
    {
      float pz0 = (float)((dz0 - ACC_FULL) * ACC_INVSCALE);
      float pz1 = (float)((dz1 - ACC_FULL) * ACC_INVSCALE);
      float ph0 = (float)((dh0 - ACC_FULL) * ACC_INVSCALE);
      float ph1 = (float)((dh1 - ACC_FULL) * ACC_INVSCALE);
      float z0 = 1.f / (1.f + expf(-(bflo(gzu) + pz0)));
      float z1 = 1.f / (1.f + expf(-(bfhi(gzu) + pz1)));
      float hp0 = tanhf(bflo(ghu) + ph0);
      float hp1 = tanhf(bfhi(ghu) + ph1);
      float h0 = hbuf[2 * tid], h1 = hbuf[2 * tid + 1];
      hbuf[2 * tid] = (1.f - z0) * h0 + z0 * hp0;
      hbuf[2 * tid + 1] = (1.f - z1) * h1 + z1 * hp1;
    }
    gzu = gzu2; ghu = ghu2;
    if (tid < 16) { grbuf[2 * tid] = bflo(gru2); grbuf[2 * tid + 1] = bfhi(gru2); }
    __syncthreads();   // barrier 2: hbuf/grbuf ready; drains zero-stores & adds
  }

  // every WG holds the full final h; slice 0 writes it out
  if (slice == 0) {
    Hout[(size_t)b * DH + 2 * tid] = hbuf[2 * tid];
    Hout[(size_t)b * DH + 2 * tid + 1] = hbuf[2 * tid + 1];
  }
}

// ---------------------------------------------------------------------------
// classifier: out[8][10] = h_final @ W_c^T
// ---------------------------------------------------------------------------
__global__ void classifier_kernel(const float* __restrict__ Hout,
                                  const float* __restrict__ Wc,
                                  float* __restrict__ out) {
  int tid = threadIdx.x;
  if (tid < 80) {
    int b = tid / 10, c = tid % 10;
    const float* h = Hout + (size_t)b * DH;
    const float* w = Wc + (size_t)c * DH;
    float s = 0.f;
    for (int i = 0; i < DH; ++i) s += h[i] * w[i];
    out[tid] = s;
  }
}

extern "C" void kernel_launch(void* const* d_in, const int* in_sizes, int n_in,
                              void* d_out, int out_size, void* d_ws, size_t ws_size,
                              hipStream_t stream) {
  const float* X = (const float*)d_in[0];
  const float* Wlm = (const float*)d_in[1];
  const float* Wz = (const float*)d_in[2];
  const float* Wr = (const float*)d_in[3];
  const float* Wh = (const float*)d_in[4];
  const float* Wc = (const float*)d_in[5];
  float* out = (float*)d_out;

  char* ws = (char*)d_ws;
  unsigned short* seqb = (unsigned short*)ws;              // 33,554,432 B
  unsigned short* G = (unsigned short*)(ws + 33554432);    // 100,663,296 B
  unsigned short* Wp = (unsigned short*)(ws + 134217728);  // 1,572,864 B
  double* ACCd = (double*)(ws + 135790592);                // 196,608 B
  float* Hout = (float*)(ws + 135987200);                  // 16,384 B

  init_state<<<96, 256, 0, stream>>>((unsigned long long*)ACCd);
  pack_w<<<768, 1024, 0, stream>>>(Wz, Wr, Wh, Wp);
  gemm1_kernel<<<dim3(512, 8), 256, 0, stream>>>(X, Wlm, seqb);
  gemm2_kernel<<<dim3(512, 24), 256, 0, stream>>>(seqb, Wp, G);

  {
    const int scan_lds = 100608;
    hipFuncSetAttribute((const void*)scan_kernel,
                        hipFuncAttributeMaxDynamicSharedMemorySize, scan_lds);
    const unsigned short* Gc = G;
    double* ACCp = ACCd;
    float* Hp = Hout;
    void* args[] = {(void*)&Gc, (void*)&Wz, (void*)&Wr, (void*)&Wh,
                    (void*)&ACCp, (void*)&Hp};
    hipLaunchCooperativeKernel((const void*)scan_kernel, dim3(NWG), dim3(256),
                               args, scan_lds, stream);
  }
  classifier_kernel<<<1, 128, 0, stream>>>(Hout, Wc, out);
}